// Round 8
// baseline (285.474 us; speedup 1.0000x reference)
//
#include <hip/hip_runtime.h>
#include <math.h>

// SchNet interaction, MFMA bf16-split, swizzled-weight design, R8.
// Nb=8, Na=1024, Nnbh=64, A=F=128, S=50.
// prep u32 layout (fragment-linear swizzled order, 1 KB/wave coalesced):
//   W1S    @0      (4096):  [ftile][kh][l][4]   W_f1 bf16, K 50->64 pad
//   W2S    @4096   (8192):  [ftile][kq][l][4]   W_f2 bf16
//   F2O_h  @12288, F2O_l @20480   W_f2out hi/lo split, swizzled
//   DEN_h  @28672, DEN_l @36864   W_dense  hi/lo split
//   IN2F_h @45056, IN2F_l @53248  W_in2f   hi/lo split
// fragment addr for (ftile,kq): (ftile*4+kq)*256 + l*4 (u32), f = 16*ftile+m.
//
// R8: g-axis (H-column) double-pass. pv is linear in S = H@W2^T, so H is
// computed and consumed in two 64-col halves sharing one 64x72 LDS buffer:
//   A(ft 0-3) | bar | gather, B(kq 0-1, +b2) | bar | A(ft 4-7) | bar | B(kq 2-3)
// fij fragments persist in registers across passes -> ZERO duplicated work
// (unlike R6's n-split). LDS 35328 -> 18944 B; target 5-6 blocks/CU (was 4).
// Phase A/B math identical to R3 (best measured, 110us). Straight-line
// template<PASS> helpers (R6-validated anti-spill); launch_bounds(256,4)
// untouched (R5 lesson: never squeeze the allocator).

#define RCUT  5.0f
#define LOG2F_ 0.69314718055994530942f
#define LOG2E_ 1.44269504088896340736f

typedef __bf16 bf16x8_t __attribute__((ext_vector_type(8)));
typedef float  f32x4_t  __attribute__((ext_vector_type(4)));

static __device__ __forceinline__ float sspf(float x) {
    // softplus(x) - ln2 = max(x,0) + ln2*log2(1 + 2^(-|x|*log2e)) - ln2
    float e  = exp2f(-LOG2E_ * fabsf(x));
    float lg = log2f(1.0f + e);
    return fmaf(lg, LOG2F_, fmaxf(x, 0.0f) - LOG2F_);
}
static __device__ __forceinline__ unsigned pack2h(__bf16 a, __bf16 b) {
    union { __bf16 h[2]; unsigned u; } un; un.h[0] = a; un.h[1] = b; return un.u;
}
static __device__ __forceinline__ unsigned pack2f(float a, float b) {
    return pack2h((__bf16)a, (__bf16)b);
}

// ---------------------------------------------------------------------------
// K0: weight prep (all swizzled conversions). 240 blocks x 256 = 61440 items.
// ---------------------------------------------------------------------------
__global__ __launch_bounds__(256) void prep_kernel(
    const float* __restrict__ W1, const float* __restrict__ W2,
    const float* __restrict__ Wb,   // W_f2out
    const float* __restrict__ Wc,   // W_dense
    const float* __restrict__ Wf,   // W_in2f
    unsigned* __restrict__ prep)
{
    int i = blockIdx.x * 256 + threadIdx.x;
    if (i < 4096) {                        // W1S (K pad 50->64)
        int sw = i >> 10, ft = (i >> 9) & 1, kh = (i >> 8) & 1;
        int sl = (i >> 2) & 63, j = i & 3;
        int sq = sl >> 4, sm = sl & 15;
        int f = 32 * sw + 16 * ft + sm;
        int c = kh * 16 + 4 * sq + j;
        int k0 = 2 * c, k1 = 2 * c + 1;
        float a = (k0 < 50) ? W1[f * 50 + k0] : 0.0f;
        float b = (k1 < 50) ? W1[f * 50 + k1] : 0.0f;
        prep[i] = pack2f(a, b);
    } else if (i < 12288) {                // W2S
        int s = i - 4096;
        int sw = s >> 11, ft = (s >> 10) & 1, kq = (s >> 8) & 3;
        int sl = (s >> 2) & 63, j = s & 3;
        int sq = sl >> 4, sm = sl & 15;
        int f = 32 * sw + 16 * ft + sm;
        int c = 16 * kq + 4 * sq + j;
        float2 wv = ((const float2*)W2)[f * 64 + c];
        prep[i] = pack2f(wv.x, wv.y);
    } else {                               // f2out / dense / in2f, hi+lo
        int s = i - 12288;
        int L = s >> 14;                   // 0: f2out, 1: dense, 2: in2f
        int r = s & 16383;
        int hl = r >> 13;                  // 0: hi, 1: lo
        int e = r & 8191;
        int sw = e >> 11, ft = (e >> 10) & 1, kq = (e >> 8) & 3;
        int sl = (e >> 2) & 63, j = e & 3;
        int sq = sl >> 4, sm = sl & 15;
        int f = 32 * sw + 16 * ft + sm;
        int c = 16 * kq + 4 * sq + j;
        const float* src = (L == 0) ? Wb : (L == 1) ? Wc : Wf;
        float2 wv = ((const float2*)src)[f * 64 + c];
        if (hl == 0) {
            prep[i] = pack2h((__bf16)wv.x, (__bf16)wv.y);
        } else {
            __bf16 h0 = (__bf16)wv.x, h1 = (__bf16)wv.y;
            prep[i] = pack2f(wv.x - (float)h0, wv.y - (float)h1);
        }
    }
}

// ---------------------------------------------------------------------------
// K1: y = x @ W_in2f^T using preconverted swizzled weights.
// 1024 blocks: (atom-tile of 16) x (f-half of 64).
// ---------------------------------------------------------------------------
__global__ __launch_bounds__(256, 4) void k1_kernel(
    const float* __restrict__ x,
    const unsigned* __restrict__ Wh, const unsigned* __restrict__ Wl,
    float* __restrict__ yout)
{
    __shared__ __bf16 Ah[16 * 136];
    __shared__ __bf16 Al[16 * 136];

    const int t = threadIdx.x;
    const int atom0 = (blockIdx.x >> 1) * 16;
    const int fh = blockIdx.x & 1;
    const int w = t >> 6, l = t & 63, m = l & 15, q = l >> 4;

    {
        const float4* A4 = (const float4*)(x + (size_t)atom0 * 128);
        unsigned* AhU = (unsigned*)Ah;
        unsigned* AlU = (unsigned*)Al;
        #pragma unroll
        for (int r = 0; r < 2; ++r) {
            int lin4 = r * 256 + t;
            int a = lin4 >> 5, k4 = lin4 & 31;
            float4 xv = A4[lin4];
            __bf16 h0=(__bf16)xv.x, h1=(__bf16)xv.y, h2=(__bf16)xv.z, h3=(__bf16)xv.w;
            int idx = a * 68 + 2 * k4;
            AhU[idx]     = pack2h(h0, h1);
            AhU[idx + 1] = pack2h(h2, h3);
            AlU[idx]     = pack2f(xv.x - (float)h0, xv.y - (float)h1);
            AlU[idx + 1] = pack2f(xv.z - (float)h2, xv.w - (float)h3);
        }
    }
    __syncthreads();

    const int ftile = fh * 4 + w;
    const int f = 16 * ftile + m;
    f32x4_t acc = {0.f, 0.f, 0.f, 0.f};
    #pragma unroll
    for (int kk = 0; kk < 4; ++kk) {
        int off = m * 136 + 32 * kk + 8 * q;
        bf16x8_t ah = *(const bf16x8_t*)&Ah[off];
        bf16x8_t al = *(const bf16x8_t*)&Al[off];
        int wo = (ftile * 4 + kk) * 256 + l * 4;
        bf16x8_t wh = *(const bf16x8_t*)(Wh + wo);
        bf16x8_t wl = *(const bf16x8_t*)(Wl + wo);
        acc = __builtin_amdgcn_mfma_f32_16x16x32_bf16(ah, wh, acc, 0, 0, 0);
        acc = __builtin_amdgcn_mfma_f32_16x16x32_bf16(ah, wl, acc, 0, 0, 0);
        acc = __builtin_amdgcn_mfma_f32_16x16x32_bf16(al, wh, acc, 0, 0, 0);
    }
    #pragma unroll
    for (int r = 0; r < 4; ++r)
        yout[(size_t)(atom0 + 4 * q + r) * 128 + f] = acc[r];
}

// ---------------------------------------------------------------------------
// K2 phase helpers (straight-line, template<PASS>).
// Phase A pass P: H[n][gloc] = ssp(fij @ W1^T + b1) for g = 64P + gloc.
// Wave w owns rows 16w..16w+15; exact R3 math/orientation.
// ---------------------------------------------------------------------------
template<int PASS>
static __device__ __forceinline__ void k2A(
    const unsigned* __restrict__ W1S, const float* __restrict__ b1,
    const bf16x8_t (&uhv)[2], const bf16x8_t (&ulv)[2],
    int w, int m, int q, int l,
    __bf16* __restrict__ Hh, __bf16* __restrict__ Hl)
{
    #pragma unroll
    for (int ft4 = 0; ft4 < 4; ++ft4) {
        const int ftile = 4 * PASS + ft4;
        float bb = b1[16 * ftile + m];
        f32x4_t acch = {bb, bb, bb, bb};
        f32x4_t accl = {0.f, 0.f, 0.f, 0.f};
        bf16x8_t w0 = *(const bf16x8_t*)(W1S + (ftile * 2 + 0) * 256 + l * 4);
        bf16x8_t w1 = *(const bf16x8_t*)(W1S + (ftile * 2 + 1) * 256 + l * 4);
        acch = __builtin_amdgcn_mfma_f32_16x16x32_bf16(uhv[0], w0, acch, 0, 0, 0);
        accl = __builtin_amdgcn_mfma_f32_16x16x32_bf16(ulv[0], w0, accl, 0, 0, 0);
        acch = __builtin_amdgcn_mfma_f32_16x16x32_bf16(uhv[1], w1, acch, 0, 0, 0);
        accl = __builtin_amdgcn_mfma_f32_16x16x32_bf16(ulv[1], w1, accl, 0, 0, 0);
        #pragma unroll
        for (int r = 0; r < 4; ++r) {
            int n = 16 * w + 4 * q + r;
            float hv = sspf(acch[r] + accl[r]);
            __bf16 hh = (__bf16)hv;
            Hh[n * 72 + 16 * ft4 + m] = hh;
            Hl[n * 72 + 16 * ft4 + m] = (__bf16)(hv - (float)hh);
        }
    }
}

// Phase B pass P: accumulate pv += cy * (H @ W2^T cols kq=2P..2P+1), with b2
// folded into pass 0 only (pv is linear in the partial sums).
template<int PASS>
static __device__ __forceinline__ void k2B(
    const unsigned* __restrict__ W2S,
    const __bf16* __restrict__ Hh, const __bf16* __restrict__ Hl,
    const float (&cy0)[16], const float (&cy1)[16],
    int m, int q, int w, int l,
    float bb2_0, float bb2_1,
    float& pv0, float& pv1)
{
    bf16x8_t w2a[2], w2b[2];
    #pragma unroll
    for (int kqL = 0; kqL < 2; ++kqL) {
        const int kq = 2 * PASS + kqL;
        w2a[kqL] = *(const bf16x8_t*)(W2S + ((w * 2 + 0) * 4 + kq) * 256 + l * 4);
        w2b[kqL] = *(const bf16x8_t*)(W2S + ((w * 2 + 1) * 4 + kq) * 256 + l * 4);
    }
    #pragma unroll
    for (int mt = 0; mt < 4; ++mt) {
        f32x4_t a0h, a1h;
        if (PASS == 0) {
            a0h = (f32x4_t){bb2_0, bb2_0, bb2_0, bb2_0};
            a1h = (f32x4_t){bb2_1, bb2_1, bb2_1, bb2_1};
        } else {
            a0h = (f32x4_t){0.f, 0.f, 0.f, 0.f};
            a1h = (f32x4_t){0.f, 0.f, 0.f, 0.f};
        }
        f32x4_t a0l = {0.f, 0.f, 0.f, 0.f};
        f32x4_t a1l = {0.f, 0.f, 0.f, 0.f};
        #pragma unroll
        for (int kqL = 0; kqL < 2; ++kqL) {
            int hoff = (16 * mt + m) * 72 + 32 * kqL + 8 * q;
            bf16x8_t hh = *(const bf16x8_t*)&Hh[hoff];
            bf16x8_t hl = *(const bf16x8_t*)&Hl[hoff];
            a0h = __builtin_amdgcn_mfma_f32_16x16x32_bf16(hh, w2a[kqL], a0h, 0, 0, 0);
            a0l = __builtin_amdgcn_mfma_f32_16x16x32_bf16(hl, w2a[kqL], a0l, 0, 0, 0);
            a1h = __builtin_amdgcn_mfma_f32_16x16x32_bf16(hh, w2b[kqL], a1h, 0, 0, 0);
            a1l = __builtin_amdgcn_mfma_f32_16x16x32_bf16(hl, w2b[kqL], a1l, 0, 0, 0);
        }
        #pragma unroll
        for (int r = 0; r < 4; ++r) {
            float s0 = a0h[r] + a0l[r];
            float s1 = a1h[r] + a1l[r];
            pv0 = fmaf(cy0[mt * 4 + r], s0, pv0);
            pv1 = fmaf(cy1[mt * 4 + r], s1, pv1);
        }
    }
}

// ---------------------------------------------------------------------------
// K2 interaction. 1 atom/block, 256 thr = 4 waves, g-split double pass.
// LDS 18944 B; fij fragments live in registers across both passes.
// ---------------------------------------------------------------------------
__global__ __launch_bounds__(256, 4) void interaction_kernel(
    const float* __restrict__ rij, const int* __restrict__ nbrs,
    const float* __restrict__ mask, const float* __restrict__ fij,
    const float* __restrict__ b1, const float* __restrict__ b2,
    const unsigned* __restrict__ W1S,   // swizzled [8][2][64][4] u32
    const unsigned* __restrict__ W2S,   // swizzled [8][4][64][4] u32
    const float* __restrict__ y, float* __restrict__ v)
{
    __shared__ __bf16 Hh[64 * 72];
    __shared__ __bf16 Hl[64 * 72];
    __shared__ float  cb[64];
    __shared__ int    nb[64];

    const int t  = threadIdx.x;
    const int a  = blockIdx.x;
    const int bi = a >> 10;
    const int p0 = a * 64;
    const int w = t >> 6, l = t & 63, m = l & 15, q = l >> 4;
    const int f0 = 32 * w + m;
    const int f1 = f0 + 16;

    if (t < 64) {
        float r = rij[p0 + t];
        cb[t] = (r <= RCUT) ? mask[p0 + t] : 0.0f;
        nb[t] = (bi << 10) + nbrs[p0 + t];
    }

    // ---- fij load + hi/lo convert, ONCE; fragments persist both passes ----
    bf16x8_t uhv[2], ulv[2];
    {
        const float* frow = fij + (size_t)(p0 + 16 * w + m) * 50;
        float kv[16];
        #pragma unroll
        for (int j2 = 0; j2 < 4; ++j2) {
            float2 xv = *(const float2*)(frow + 8 * q + 2 * j2);
            kv[2 * j2] = xv.x; kv[2 * j2 + 1] = xv.y;
        }
        #pragma unroll
        for (int j2 = 0; j2 < 4; ++j2) {
            int k = 32 + 8 * q + 2 * j2;
            float2 xv = make_float2(0.f, 0.f);
            if (k < 50) xv = *(const float2*)(frow + k);
            kv[8 + 2 * j2] = xv.x; kv[9 + 2 * j2] = xv.y;
        }
        union { __bf16 e[16]; bf16x8_t v8[2]; } uh, ul;
        #pragma unroll
        for (int k = 0; k < 16; ++k) {
            __bf16 hi = (__bf16)kv[k];
            uh.e[k] = hi;
            ul.e[k] = (__bf16)(kv[k] - (float)hi);
        }
        uhv[0] = uh.v8[0]; uhv[1] = uh.v8[1];
        ulv[0] = ul.v8[0]; ulv[1] = ul.v8[1];
    }

    // ---- pass 0 ----
    k2A<0>(W1S, b1, uhv, ulv, w, m, q, l, Hh, Hl);
    __syncthreads();

    // gather ONCE (drains under pass-0 MFMAs, persists through pass 1)
    float cy0[16], cy1[16];
    #pragma unroll
    for (int i = 0; i < 16; ++i) {
        int n = 16 * (i >> 2) + 4 * q + (i & 3);
        const float* yrow = y + (size_t)nb[n] * 128;
        float cn = cb[n];
        cy0[i] = cn * yrow[f0];
        cy1[i] = cn * yrow[f1];
    }

    const float bb2_0 = b2[f0], bb2_1 = b2[f1];
    float pv0 = 0.0f, pv1 = 0.0f;
    k2B<0>(W2S, Hh, Hl, cy0, cy1, m, q, w, l, bb2_0, bb2_1, pv0, pv1);
    __syncthreads();   // H about to be overwritten

    // ---- pass 1 ----
    k2A<1>(W1S, b1, uhv, ulv, w, m, q, l, Hh, Hl);
    __syncthreads();
    k2B<1>(W2S, Hh, Hl, cy0, cy1, m, q, w, l, bb2_0, bb2_1, pv0, pv1);

    pv0 += __shfl_xor(pv0, 16);
    pv0 += __shfl_xor(pv0, 32);
    pv1 += __shfl_xor(pv1, 16);
    pv1 += __shfl_xor(pv1, 32);
    if (l < 16) {
        v[(size_t)a * 128 + f0] = pv0;
        v[(size_t)a * 128 + f1] = pv1;
    }
}

// ---------------------------------------------------------------------------
// K3: two chained dense layers, swizzled coalesced weight loads.
// ---------------------------------------------------------------------------
__global__ __launch_bounds__(256, 4) void mgemm2_kernel(
    const float* A,
    const unsigned* __restrict__ W1h, const unsigned* __restrict__ W1l,
    const float* __restrict__ bias1, int nssp1,
    const unsigned* __restrict__ W2h, const unsigned* __restrict__ W2l,
    const float* __restrict__ bias2, int nssp2,
    float* C)
{
    extern __shared__ float smf[];
    __bf16* Ah = (__bf16*)smf;              // [16][136]
    __bf16* Al = (__bf16*)(smf + 1088);
    unsigned* AhU = (unsigned*)Ah;
    unsigned* AlU = (unsigned*)Al;

    const int t = threadIdx.x;
    const int atom0 = blockIdx.x * 16;
    const int w = t >> 6, l = t & 63, m = l & 15, q = l >> 4;

    {
        const float4* A4 = (const float4*)(A + (size_t)atom0 * 128);
        #pragma unroll
        for (int r = 0; r < 2; ++r) {
            int lin4 = r * 256 + t;
            int a = lin4 >> 5, k4 = lin4 & 31;
            float4 xv = A4[lin4];
            __bf16 h0=(__bf16)xv.x, h1=(__bf16)xv.y, h2=(__bf16)xv.z, h3=(__bf16)xv.w;
            int idx = a * 68 + 2 * k4;
            AhU[idx]     = pack2h(h0, h1);
            AhU[idx + 1] = pack2h(h2, h3);
            AlU[idx]     = pack2f(xv.x - (float)h0, xv.y - (float)h1);
            AlU[idx + 1] = pack2f(xv.z - (float)h2, xv.w - (float)h3);
        }
    }
    __syncthreads();

    bf16x8_t ah[4], al[4];
    #pragma unroll
    for (int kk = 0; kk < 4; ++kk) {
        int off = m * 136 + 32 * kk + 8 * q;
        ah[kk] = *(const bf16x8_t*)&Ah[off];
        al[kk] = *(const bf16x8_t*)&Al[off];
    }
    f32x4_t acc[2];
    int fidx[2];
    #pragma unroll
    for (int ft = 0; ft < 2; ++ft) {
        fidx[ft] = 16 * (2 * w + ft) + m;
        float b = bias1 ? bias1[fidx[ft]] : 0.0f;
        acc[ft] = (f32x4_t){b, b, b, b};
    }
    #pragma unroll
    for (int ft = 0; ft < 2; ++ft) {
        #pragma unroll
        for (int kk = 0; kk < 4; ++kk) {
            int wo = ((2 * w + ft) * 4 + kk) * 256 + l * 4;
            bf16x8_t wh = *(const bf16x8_t*)(W1h + wo);
            bf16x8_t wl = *(const bf16x8_t*)(W1l + wo);
            acc[ft] = __builtin_amdgcn_mfma_f32_16x16x32_bf16(ah[kk], wh, acc[ft], 0, 0, 0);
            acc[ft] = __builtin_amdgcn_mfma_f32_16x16x32_bf16(ah[kk], wl, acc[ft], 0, 0, 0);
            acc[ft] = __builtin_amdgcn_mfma_f32_16x16x32_bf16(al[kk], wh, acc[ft], 0, 0, 0);
        }
    }
    #pragma unroll
    for (int ft = 0; ft < 2; ++ft)
        #pragma unroll
        for (int r = 0; r < 4; ++r) {
            float o = acc[ft][r];
            if (nssp1 >= 1) o = sspf(o);
            if (nssp1 >= 2) o = sspf(o);
            acc[ft][r] = o;
        }

    __syncthreads();
    #pragma unroll
    for (int ft = 0; ft < 2; ++ft)
        #pragma unroll
        for (int r = 0; r < 4; ++r) {
            float o = acc[ft][r];
            __bf16 hh = (__bf16)o;
            Ah[(4 * q + r) * 136 + fidx[ft]] = hh;
            Al[(4 * q + r) * 136 + fidx[ft]] = (__bf16)(o - (float)hh);
        }
    __syncthreads();

    #pragma unroll
    for (int kk = 0; kk < 4; ++kk) {
        int off = m * 136 + 32 * kk + 8 * q;
        ah[kk] = *(const bf16x8_t*)&Ah[off];
        al[kk] = *(const bf16x8_t*)&Al[off];
    }
    #pragma unroll
    for (int ft = 0; ft < 2; ++ft) {
        float b = bias2 ? bias2[fidx[ft]] : 0.0f;
        acc[ft] = (f32x4_t){b, b, b, b};
    }
    #pragma unroll
    for (int ft = 0; ft < 2; ++ft) {
        #pragma unroll
        for (int kk = 0; kk < 4; ++kk) {
            int wo = ((2 * w + ft) * 4 + kk) * 256 + l * 4;
            bf16x8_t wh = *(const bf16x8_t*)(W2h + wo);
            bf16x8_t wl = *(const bf16x8_t*)(W2l + wo);
            acc[ft] = __builtin_amdgcn_mfma_f32_16x16x32_bf16(ah[kk], wh, acc[ft], 0, 0, 0);
            acc[ft] = __builtin_amdgcn_mfma_f32_16x16x32_bf16(ah[kk], wl, acc[ft], 0, 0, 0);
            acc[ft] = __builtin_amdgcn_mfma_f32_16x16x32_bf16(al[kk], wh, acc[ft], 0, 0, 0);
        }
    }
    #pragma unroll
    for (int ft = 0; ft < 2; ++ft)
        #pragma unroll
        for (int r = 0; r < 4; ++r) {
            float o = acc[ft][r];
            if (nssp2 >= 1) o = sspf(o);
            if (nssp2 >= 2) o = sspf(o);
            C[(size_t)(atom0 + 4 * q + r) * 128 + fidx[ft]] = o;
        }
}

// ---------------------------------------------------------------------------
extern "C" void kernel_launch(void* const* d_in, const int* in_sizes, int n_in,
                              void* d_out, int out_size, void* d_ws, size_t ws_size,
                              hipStream_t stream) {
    const float* x        = (const float*)d_in[0];
    const float* rij      = (const float*)d_in[1];
    const int*   nbrs     = (const int*)  d_in[2];
    const float* mask     = (const float*)d_in[3];
    const float* fij      = (const float*)d_in[4];
    const float* W_in2f   = (const float*)d_in[5];
    const float* W_f1     = (const float*)d_in[6];
    const float* b_f1     = (const float*)d_in[7];
    const float* W_f2     = (const float*)d_in[8];
    const float* b_f2     = (const float*)d_in[9];
    const float* W_f2out  = (const float*)d_in[10];
    const float* b_f2out  = (const float*)d_in[11];
    const float* W_dense  = (const float*)d_in[12];
    const float* b_dense  = (const float*)d_in[13];
    float* out = (float*)d_out;

    // ws: y [8192][128] f32 @0 (4 MB) | prep 240 KB @4 MB.
    float*    y    = (float*)d_ws;
    unsigned* prep = (unsigned*)((char*)d_ws + (4u << 20));
    const unsigned* W1S    = prep;
    const unsigned* W2S    = prep + 4096;
    const unsigned* f2o_h  = prep + 12288, *f2o_l  = prep + 20480;
    const unsigned* den_h  = prep + 28672, *den_l  = prep + 36864;
    const unsigned* in2f_h = prep + 45056, *in2f_l = prep + 53248;

    const int MG2_LDS = 2176 * 4;    // 8704 B

    // K0: all weight prep (61440 items)
    prep_kernel<<<240, 256, 0, stream>>>(W_f1, W_f2, W_f2out, W_dense, W_in2f, prep);
    // K1: y = x @ W_in2f^T  (preconverted weights, 1024 blocks)
    k1_kernel<<<1024, 256, 0, stream>>>(x, in2f_h, in2f_l, y);
    // K2: filter net + cutoff + gather + aggregate -> d_out (v)
    interaction_kernel<<<8192, 256, 0, stream>>>(
        rij, nbrs, mask, fij, b_f1, b_f2, W1S, W2S, y, out);
    // K3: out = ssp(ssp(v@W_f2out^T+b)) @ W_dense^T + b_dense, in-place
    mgemm2_kernel<<<512, 256, MG2_LDS, stream>>>(
        out, f2o_h, f2o_l, b_f2out, 2, den_h, den_l, b_dense, 0, out);
}

// Round 9
// 276.093 us; speedup vs baseline: 1.0340x; 1.0340x over previous
//
#include <hip/hip_runtime.h>
#include <math.h>

// SchNet interaction, MFMA bf16-split, swizzled-weight design, R9.
// Nb=8, Na=1024, Nnbh=64, A=F=128, S=50.
// prep u32 layout (fragment-linear swizzled order, 1 KB/wave coalesced):
//   W1S    @0      (4096):  [ftile][kh][l][4]   W_f1 bf16, K 50->64 pad
//   W2S    @4096   (8192):  [ftile][kq][l][4]   W_f2 bf16
//   F2O_h  @12288, F2O_l @20480   W_f2out hi/lo split, swizzled
//   DEN_h  @28672, DEN_l @36864   W_dense  hi/lo split
//   IN2F_h @45056, IN2F_l @53248  W_in2f   hi/lo split
// fragment addr for (ftile,kq): (ftile*4+kq)*256 + l*4 (u32), f = 16*ftile+m.
//
// R9: ZERO-mid-barrier K2. Evidence: R3(1 bar)=110, R6(3)=120, R8(4)=139 --
// ~10us per barrier. Phase B re-partitioned by ROWS: wave w's B consumes the
// H rows 16w..16w+15 that wave w itself wrote in A -> same-wave LDS dep only
// (lgkmcnt, no __syncthreads). b2 folded per-row (each row in exactly one
// wave). Per-wave partials pv_w[f] reduced across waves by ONE tail barrier
// + 4-way add (trivial work after it). Phase A identical to R3 (best
// measured). H ds_reads halve (32->16); cb/nb LDS staging removed; y-gathers
// issued before A (fij first in vmcnt order) drain under A's compute.

#define RCUT  5.0f
#define LOG2F_ 0.69314718055994530942f
#define LOG2E_ 1.44269504088896340736f

typedef __bf16 bf16x8_t __attribute__((ext_vector_type(8)));
typedef float  f32x4_t  __attribute__((ext_vector_type(4)));

static __device__ __forceinline__ float sspf(float x) {
    // softplus(x) - ln2 = max(x,0) + ln2*log2(1 + 2^(-|x|*log2e)) - ln2
    float e  = exp2f(-LOG2E_ * fabsf(x));
    float lg = log2f(1.0f + e);
    return fmaf(lg, LOG2F_, fmaxf(x, 0.0f) - LOG2F_);
}
static __device__ __forceinline__ unsigned pack2h(__bf16 a, __bf16 b) {
    union { __bf16 h[2]; unsigned u; } un; un.h[0] = a; un.h[1] = b; return un.u;
}
static __device__ __forceinline__ unsigned pack2f(float a, float b) {
    return pack2h((__bf16)a, (__bf16)b);
}

// ---------------------------------------------------------------------------
// K0: weight prep (all swizzled conversions). 240 blocks x 256 = 61440 items.
// ---------------------------------------------------------------------------
__global__ __launch_bounds__(256) void prep_kernel(
    const float* __restrict__ W1, const float* __restrict__ W2,
    const float* __restrict__ Wb,   // W_f2out
    const float* __restrict__ Wc,   // W_dense
    const float* __restrict__ Wf,   // W_in2f
    unsigned* __restrict__ prep)
{
    int i = blockIdx.x * 256 + threadIdx.x;
    if (i < 4096) {                        // W1S (K pad 50->64)
        int sw = i >> 10, ft = (i >> 9) & 1, kh = (i >> 8) & 1;
        int sl = (i >> 2) & 63, j = i & 3;
        int sq = sl >> 4, sm = sl & 15;
        int f = 32 * sw + 16 * ft + sm;
        int c = kh * 16 + 4 * sq + j;
        int k0 = 2 * c, k1 = 2 * c + 1;
        float a = (k0 < 50) ? W1[f * 50 + k0] : 0.0f;
        float b = (k1 < 50) ? W1[f * 50 + k1] : 0.0f;
        prep[i] = pack2f(a, b);
    } else if (i < 12288) {                // W2S
        int s = i - 4096;
        int sw = s >> 11, ft = (s >> 10) & 1, kq = (s >> 8) & 3;
        int sl = (s >> 2) & 63, j = s & 3;
        int sq = sl >> 4, sm = sl & 15;
        int f = 32 * sw + 16 * ft + sm;
        int c = 16 * kq + 4 * sq + j;
        float2 wv = ((const float2*)W2)[f * 64 + c];
        prep[i] = pack2f(wv.x, wv.y);
    } else {                               // f2out / dense / in2f, hi+lo
        int s = i - 12288;
        int L = s >> 14;                   // 0: f2out, 1: dense, 2: in2f
        int r = s & 16383;
        int hl = r >> 13;                  // 0: hi, 1: lo
        int e = r & 8191;
        int sw = e >> 11, ft = (e >> 10) & 1, kq = (e >> 8) & 3;
        int sl = (e >> 2) & 63, j = e & 3;
        int sq = sl >> 4, sm = sl & 15;
        int f = 32 * sw + 16 * ft + sm;
        int c = 16 * kq + 4 * sq + j;
        const float* src = (L == 0) ? Wb : (L == 1) ? Wc : Wf;
        float2 wv = ((const float2*)src)[f * 64 + c];
        if (hl == 0) {
            prep[i] = pack2h((__bf16)wv.x, (__bf16)wv.y);
        } else {
            __bf16 h0 = (__bf16)wv.x, h1 = (__bf16)wv.y;
            prep[i] = pack2f(wv.x - (float)h0, wv.y - (float)h1);
        }
    }
}

// ---------------------------------------------------------------------------
// K1: y = x @ W_in2f^T using preconverted swizzled weights.
// 1024 blocks: (atom-tile of 16) x (f-half of 64).
// ---------------------------------------------------------------------------
__global__ __launch_bounds__(256, 4) void k1_kernel(
    const float* __restrict__ x,
    const unsigned* __restrict__ Wh, const unsigned* __restrict__ Wl,
    float* __restrict__ yout)
{
    __shared__ __bf16 Ah[16 * 136];
    __shared__ __bf16 Al[16 * 136];

    const int t = threadIdx.x;
    const int atom0 = (blockIdx.x >> 1) * 16;
    const int fh = blockIdx.x & 1;
    const int w = t >> 6, l = t & 63, m = l & 15, q = l >> 4;

    {
        const float4* A4 = (const float4*)(x + (size_t)atom0 * 128);
        unsigned* AhU = (unsigned*)Ah;
        unsigned* AlU = (unsigned*)Al;
        #pragma unroll
        for (int r = 0; r < 2; ++r) {
            int lin4 = r * 256 + t;
            int a = lin4 >> 5, k4 = lin4 & 31;
            float4 xv = A4[lin4];
            __bf16 h0=(__bf16)xv.x, h1=(__bf16)xv.y, h2=(__bf16)xv.z, h3=(__bf16)xv.w;
            int idx = a * 68 + 2 * k4;
            AhU[idx]     = pack2h(h0, h1);
            AhU[idx + 1] = pack2h(h2, h3);
            AlU[idx]     = pack2f(xv.x - (float)h0, xv.y - (float)h1);
            AlU[idx + 1] = pack2f(xv.z - (float)h2, xv.w - (float)h3);
        }
    }
    __syncthreads();

    const int ftile = fh * 4 + w;
    const int f = 16 * ftile + m;
    f32x4_t acc = {0.f, 0.f, 0.f, 0.f};
    #pragma unroll
    for (int kk = 0; kk < 4; ++kk) {
        int off = m * 136 + 32 * kk + 8 * q;
        bf16x8_t ah = *(const bf16x8_t*)&Ah[off];
        bf16x8_t al = *(const bf16x8_t*)&Al[off];
        int wo = (ftile * 4 + kk) * 256 + l * 4;
        bf16x8_t wh = *(const bf16x8_t*)(Wh + wo);
        bf16x8_t wl = *(const bf16x8_t*)(Wl + wo);
        acc = __builtin_amdgcn_mfma_f32_16x16x32_bf16(ah, wh, acc, 0, 0, 0);
        acc = __builtin_amdgcn_mfma_f32_16x16x32_bf16(ah, wl, acc, 0, 0, 0);
        acc = __builtin_amdgcn_mfma_f32_16x16x32_bf16(al, wh, acc, 0, 0, 0);
    }
    #pragma unroll
    for (int r = 0; r < 4; ++r)
        yout[(size_t)(atom0 + 4 * q + r) * 128 + f] = acc[r];
}

// ---------------------------------------------------------------------------
// K2 interaction. 1 atom/block, 256 thr = 4 waves, NO mid-barrier.
// Wave w: A writes H rows 16w..16w+15; B consumes those SAME rows over all
// 128 f-cols (same-wave LDS dep only). One tail barrier for 4-way reduce.
// ---------------------------------------------------------------------------
__global__ __launch_bounds__(256, 4) void interaction_kernel(
    const float* __restrict__ rij, const int* __restrict__ nbrs,
    const float* __restrict__ mask, const float* __restrict__ fij,
    const float* __restrict__ b1, const float* __restrict__ b2,
    const unsigned* __restrict__ W1S,   // swizzled [8][2][64][4] u32
    const unsigned* __restrict__ W2S,   // swizzled [8][4][64][4] u32
    const float* __restrict__ y, float* __restrict__ v)
{
    __shared__ __bf16 Hh[64 * 136];
    __shared__ __bf16 Hl[64 * 136];
    __shared__ float  red[512];

    const int t  = threadIdx.x;
    const int a  = blockIdx.x;
    const int bi = a >> 10;
    const int p0 = a * 64;
    const int w = t >> 6, l = t & 63, m = l & 15, q = l >> 4;

    // ---- fij loads FIRST (oldest in vmcnt order) ----
    const float* frow = fij + (size_t)(p0 + 16 * w + m) * 50;
    float kv[16];
    #pragma unroll
    for (int j2 = 0; j2 < 4; ++j2) {
        float2 xv = *(const float2*)(frow + 8 * q + 2 * j2);
        kv[2 * j2] = xv.x; kv[2 * j2 + 1] = xv.y;
    }
    #pragma unroll
    for (int j2 = 0; j2 < 4; ++j2) {
        int k = 32 + 8 * q + 2 * j2;
        float2 xv = make_float2(0.f, 0.f);
        if (k < 50) xv = *(const float2*)(frow + k);
        kv[8 + 2 * j2] = xv.x; kv[9 + 2 * j2] = xv.y;
    }

    // ---- neighbor metadata + y-gathers for THIS wave's rows ----
    // (issued after fij; drain under phase-A compute)
    int   nbr_[4];
    float cb_[4];
    #pragma unroll
    for (int r = 0; r < 4; ++r) {
        int n = p0 + 16 * w + 4 * q + r;
        float rr = rij[n];
        cb_[r] = (rr <= RCUT) ? mask[n] : 0.0f;
        nbr_[r] = (bi << 10) + nbrs[n];
    }
    float yv[32];
    #pragma unroll
    for (int r = 0; r < 4; ++r) {
        const float* yrow = y + (size_t)nbr_[r] * 128 + m;
        #pragma unroll
        for (int ftB = 0; ftB < 8; ++ftB)
            yv[r * 8 + ftB] = yrow[16 * ftB];
    }

    // ---- phase A (identical math to R3): H rows 16w+4q+r, all 128 g ----
    {
        union { __bf16 e[16]; bf16x8_t v8[2]; } uh, ul;
        #pragma unroll
        for (int k = 0; k < 16; ++k) {
            __bf16 hi = (__bf16)kv[k];
            uh.e[k] = hi;
            ul.e[k] = (__bf16)(kv[k] - (float)hi);
        }
        #pragma unroll 2
        for (int ftile = 0; ftile < 8; ++ftile) {
            float bb = b1[16 * ftile + m];
            f32x4_t acch = {bb, bb, bb, bb};
            f32x4_t accl = {0.f, 0.f, 0.f, 0.f};
            bf16x8_t w0 = *(const bf16x8_t*)(W1S + (ftile * 2 + 0) * 256 + l * 4);
            bf16x8_t w1 = *(const bf16x8_t*)(W1S + (ftile * 2 + 1) * 256 + l * 4);
            acch = __builtin_amdgcn_mfma_f32_16x16x32_bf16(uh.v8[0], w0, acch, 0, 0, 0);
            accl = __builtin_amdgcn_mfma_f32_16x16x32_bf16(ul.v8[0], w0, accl, 0, 0, 0);
            acch = __builtin_amdgcn_mfma_f32_16x16x32_bf16(uh.v8[1], w1, acch, 0, 0, 0);
            accl = __builtin_amdgcn_mfma_f32_16x16x32_bf16(ul.v8[1], w1, accl, 0, 0, 0);
            #pragma unroll
            for (int r = 0; r < 4; ++r) {
                int n = 16 * w + 4 * q + r;
                float hv = sspf(acch[r] + accl[r]);
                __bf16 hh = (__bf16)hv;
                Hh[n * 136 + 16 * ftile + m] = hh;
                Hl[n * 136 + 16 * ftile + m] = (__bf16)(hv - (float)hh);
            }
        }
    }
    // NO BARRIER: wave w's phase B reads only rows 16w..16w+15 (own writes).

    // cy = cn * y  (y drained under phase A)
    float cy[32];
    #pragma unroll
    for (int r = 0; r < 4; ++r)
        #pragma unroll
        for (int ftB = 0; ftB < 8; ++ftB)
            cy[r * 8 + ftB] = cb_[r] * yv[r * 8 + ftB];

    // ---- phase B: S rows 16w..16w+15 x all 128 f, own-wave LDS only ----
    float partial[8];
    #pragma unroll
    for (int h2 = 0; h2 < 2; ++h2) {
        f32x4_t acch[4], accl[4];
        #pragma unroll
        for (int j = 0; j < 4; ++j) {
            int ftB = 4 * h2 + j;
            float bb = b2[16 * ftB + m];
            acch[j] = (f32x4_t){bb, bb, bb, bb};
            accl[j] = (f32x4_t){0.f, 0.f, 0.f, 0.f};
        }
        #pragma unroll
        for (int kq = 0; kq < 4; ++kq) {
            int hoff = (16 * w + m) * 136 + 32 * kq + 8 * q;
            bf16x8_t hh = *(const bf16x8_t*)&Hh[hoff];
            bf16x8_t hl = *(const bf16x8_t*)&Hl[hoff];
            #pragma unroll
            for (int j = 0; j < 4; ++j) {
                int ftB = 4 * h2 + j;
                bf16x8_t w2 = *(const bf16x8_t*)(W2S + (ftB * 4 + kq) * 256 + l * 4);
                acch[j] = __builtin_amdgcn_mfma_f32_16x16x32_bf16(hh, w2, acch[j], 0, 0, 0);
                accl[j] = __builtin_amdgcn_mfma_f32_16x16x32_bf16(hl, w2, accl[j], 0, 0, 0);
            }
        }
        #pragma unroll
        for (int j = 0; j < 4; ++j) {
            int ftB = 4 * h2 + j;
            float s = 0.0f;
            #pragma unroll
            for (int r = 0; r < 4; ++r)
                s = fmaf(cy[r * 8 + ftB], acch[j][r] + accl[j][r], s);
            partial[ftB] = s;
        }
    }

    // ---- reduce over q within wave, then over waves via tiny LDS tail ----
    #pragma unroll
    for (int ftB = 0; ftB < 8; ++ftB) {
        partial[ftB] += __shfl_xor(partial[ftB], 16);
        partial[ftB] += __shfl_xor(partial[ftB], 32);
    }
    if (q == 0) {
        #pragma unroll
        for (int ftB = 0; ftB < 8; ++ftB)
            red[w * 128 + 16 * ftB + m] = partial[ftB];
    }
    __syncthreads();   // tail-only barrier (trivial work after)
    if (t < 128) {
        float s = red[t] + red[128 + t] + red[256 + t] + red[384 + t];
        v[(size_t)a * 128 + t] = s;
    }
}

// ---------------------------------------------------------------------------
// K3: two chained dense layers, swizzled coalesced weight loads.
// ---------------------------------------------------------------------------
__global__ __launch_bounds__(256, 4) void mgemm2_kernel(
    const float* A,
    const unsigned* __restrict__ W1h, const unsigned* __restrict__ W1l,
    const float* __restrict__ bias1, int nssp1,
    const unsigned* __restrict__ W2h, const unsigned* __restrict__ W2l,
    const float* __restrict__ bias2, int nssp2,
    float* C)
{
    extern __shared__ float smf[];
    __bf16* Ah = (__bf16*)smf;              // [16][136]
    __bf16* Al = (__bf16*)(smf + 1088);
    unsigned* AhU = (unsigned*)Ah;
    unsigned* AlU = (unsigned*)Al;

    const int t = threadIdx.x;
    const int atom0 = blockIdx.x * 16;
    const int w = t >> 6, l = t & 63, m = l & 15, q = l >> 4;

    {
        const float4* A4 = (const float4*)(A + (size_t)atom0 * 128);
        #pragma unroll
        for (int r = 0; r < 2; ++r) {
            int lin4 = r * 256 + t;
            int a = lin4 >> 5, k4 = lin4 & 31;
            float4 xv = A4[lin4];
            __bf16 h0=(__bf16)xv.x, h1=(__bf16)xv.y, h2=(__bf16)xv.z, h3=(__bf16)xv.w;
            int idx = a * 68 + 2 * k4;
            AhU[idx]     = pack2h(h0, h1);
            AhU[idx + 1] = pack2h(h2, h3);
            AlU[idx]     = pack2f(xv.x - (float)h0, xv.y - (float)h1);
            AlU[idx + 1] = pack2f(xv.z - (float)h2, xv.w - (float)h3);
        }
    }
    __syncthreads();

    bf16x8_t ah[4], al[4];
    #pragma unroll
    for (int kk = 0; kk < 4; ++kk) {
        int off = m * 136 + 32 * kk + 8 * q;
        ah[kk] = *(const bf16x8_t*)&Ah[off];
        al[kk] = *(const bf16x8_t*)&Al[off];
    }
    f32x4_t acc[2];
    int fidx[2];
    #pragma unroll
    for (int ft = 0; ft < 2; ++ft) {
        fidx[ft] = 16 * (2 * w + ft) + m;
        float b = bias1 ? bias1[fidx[ft]] : 0.0f;
        acc[ft] = (f32x4_t){b, b, b, b};
    }
    #pragma unroll
    for (int ft = 0; ft < 2; ++ft) {
        #pragma unroll
        for (int kk = 0; kk < 4; ++kk) {
            int wo = ((2 * w + ft) * 4 + kk) * 256 + l * 4;
            bf16x8_t wh = *(const bf16x8_t*)(W1h + wo);
            bf16x8_t wl = *(const bf16x8_t*)(W1l + wo);
            acc[ft] = __builtin_amdgcn_mfma_f32_16x16x32_bf16(ah[kk], wh, acc[ft], 0, 0, 0);
            acc[ft] = __builtin_amdgcn_mfma_f32_16x16x32_bf16(ah[kk], wl, acc[ft], 0, 0, 0);
            acc[ft] = __builtin_amdgcn_mfma_f32_16x16x32_bf16(al[kk], wh, acc[ft], 0, 0, 0);
        }
    }
    #pragma unroll
    for (int ft = 0; ft < 2; ++ft)
        #pragma unroll
        for (int r = 0; r < 4; ++r) {
            float o = acc[ft][r];
            if (nssp1 >= 1) o = sspf(o);
            if (nssp1 >= 2) o = sspf(o);
            acc[ft][r] = o;
        }

    __syncthreads();
    #pragma unroll
    for (int ft = 0; ft < 2; ++ft)
        #pragma unroll
        for (int r = 0; r < 4; ++r) {
            float o = acc[ft][r];
            __bf16 hh = (__bf16)o;
            Ah[(4 * q + r) * 136 + fidx[ft]] = hh;
            Al[(4 * q + r) * 136 + fidx[ft]] = (__bf16)(o - (float)hh);
        }
    __syncthreads();

    #pragma unroll
    for (int kk = 0; kk < 4; ++kk) {
        int off = m * 136 + 32 * kk + 8 * q;
        ah[kk] = *(const bf16x8_t*)&Ah[off];
        al[kk] = *(const bf16x8_t*)&Al[off];
    }
    #pragma unroll
    for (int ft = 0; ft < 2; ++ft) {
        float b = bias2 ? bias2[fidx[ft]] : 0.0f;
        acc[ft] = (f32x4_t){b, b, b, b};
    }
    #pragma unroll
    for (int ft = 0; ft < 2; ++ft) {
        #pragma unroll
        for (int kk = 0; kk < 4; ++kk) {
            int wo = ((2 * w + ft) * 4 + kk) * 256 + l * 4;
            bf16x8_t wh = *(const bf16x8_t*)(W2h + wo);
            bf16x8_t wl = *(const bf16x8_t*)(W2l + wo);
            acc[ft] = __builtin_amdgcn_mfma_f32_16x16x32_bf16(ah[kk], wh, acc[ft], 0, 0, 0);
            acc[ft] = __builtin_amdgcn_mfma_f32_16x16x32_bf16(ah[kk], wl, acc[ft], 0, 0, 0);
            acc[ft] = __builtin_amdgcn_mfma_f32_16x16x32_bf16(al[kk], wh, acc[ft], 0, 0, 0);
        }
    }
    #pragma unroll
    for (int ft = 0; ft < 2; ++ft)
        #pragma unroll
        for (int r = 0; r < 4; ++r) {
            float o = acc[ft][r];
            if (nssp2 >= 1) o = sspf(o);
            if (nssp2 >= 2) o = sspf(o);
            C[(size_t)(atom0 + 4 * q + r) * 128 + fidx[ft]] = o;
        }
}

// ---------------------------------------------------------------------------
extern "C" void kernel_launch(void* const* d_in, const int* in_sizes, int n_in,
                              void* d_out, int out_size, void* d_ws, size_t ws_size,
                              hipStream_t stream) {
    const float* x        = (const float*)d_in[0];
    const float* rij      = (const float*)d_in[1];
    const int*   nbrs     = (const int*)  d_in[2];
    const float* mask     = (const float*)d_in[3];
    const float* fij      = (const float*)d_in[4];
    const float* W_in2f   = (const float*)d_in[5];
    const float* W_f1     = (const float*)d_in[6];
    const float* b_f1     = (const float*)d_in[7];
    const float* W_f2     = (const float*)d_in[8];
    const float* b_f2     = (const float*)d_in[9];
    const float* W_f2out  = (const float*)d_in[10];
    const float* b_f2out  = (const float*)d_in[11];
    const float* W_dense  = (const float*)d_in[12];
    const float* b_dense  = (const float*)d_in[13];
    float* out = (float*)d_out;

    // ws: y [8192][128] f32 @0 (4 MB) | prep 240 KB @4 MB.
    float*    y    = (float*)d_ws;
    unsigned* prep = (unsigned*)((char*)d_ws + (4u << 20));
    const unsigned* W1S    = prep;
    const unsigned* W2S    = prep + 4096;
    const unsigned* f2o_h  = prep + 12288, *f2o_l  = prep + 20480;
    const unsigned* den_h  = prep + 28672, *den_l  = prep + 36864;
    const unsigned* in2f_h = prep + 45056, *in2f_l = prep + 53248;

    const int MG2_LDS = 2176 * 4;    // 8704 B

    // K0: all weight prep (61440 items)
    prep_kernel<<<240, 256, 0, stream>>>(W_f1, W_f2, W_f2out, W_dense, W_in2f, prep);
    // K1: y = x @ W_in2f^T  (preconverted weights, 1024 blocks)
    k1_kernel<<<1024, 256, 0, stream>>>(x, in2f_h, in2f_l, y);
    // K2: filter net + cutoff + gather + aggregate -> d_out (v)
    interaction_kernel<<<8192, 256, 0, stream>>>(
        rij, nbrs, mask, fij, b_f1, b_f2, W1S, W2S, y, out);
    // K3: out = ssp(ssp(v@W_f2out^T+b)) @ W_dense^T + b_dense, in-place
    mgemm2_kernel<<<512, 256, MG2_LDS, stream>>>(
        out, f2o_h, f2o_l, b_f2out, 2, den_h, den_l, b_dense, 0, out);
}

// Round 10
// 254.534 us; speedup vs baseline: 1.1216x; 1.0847x over previous
//
#include <hip/hip_runtime.h>
#include <math.h>

// SchNet interaction, MFMA bf16-split, swizzled-weight design, R10 (= R3).
// Nb=8, Na=1024, Nnbh=64, A=F=128, S=50.
// prep u32 layout (fragment-linear swizzled order, 1 KB/wave coalesced):
//   W1S    @0      (4096):  [ftile][kh][l][4]   W_f1 bf16, K 50->64 pad
//   W2S    @4096   (8192):  [ftile][kq][l][4]   W_f2 bf16
//   F2O_h  @12288, F2O_l @20480   W_f2out hi/lo split, swizzled
//   DEN_h  @28672, DEN_l @36864   W_dense  hi/lo split
//   IN2F_h @45056, IN2F_l @53248  W_in2f   hi/lo split
// fragment addr for (ftile,kq): (ftile*4+kq)*256 + l*4 (u32), f = 16*ftile+m.
//
// R10: restore of R3, the best-measured kernel (K2 110.3us, total 255.3us).
// Session evidence (R2,R6,R7,R8,R9 all >= 120us): occupancy, barrier count,
// bank conflicts, gather placement, and LDS footprint were each isolated and
// falsified as levers. R3's arrangement -- fij loaded+converted once/thread,
// W2 frags hoisted (L2-resident, drain under phase A), ONE barrier, y-gather
// issued en-bloc after it -- is the empirical optimum of this decomposition.

#define RCUT  5.0f
#define LOG2F_ 0.69314718055994530942f
#define LOG2E_ 1.44269504088896340736f

typedef __bf16 bf16x8_t __attribute__((ext_vector_type(8)));
typedef float  f32x4_t  __attribute__((ext_vector_type(4)));

static __device__ __forceinline__ float sspf(float x) {
    // softplus(x) - ln2 = max(x,0) + ln2*log2(1 + 2^(-|x|*log2e)) - ln2
    float e  = exp2f(-LOG2E_ * fabsf(x));
    float lg = log2f(1.0f + e);
    return fmaf(lg, LOG2F_, fmaxf(x, 0.0f) - LOG2F_);
}
static __device__ __forceinline__ unsigned pack2h(__bf16 a, __bf16 b) {
    union { __bf16 h[2]; unsigned u; } un; un.h[0] = a; un.h[1] = b; return un.u;
}
static __device__ __forceinline__ unsigned pack2f(float a, float b) {
    return pack2h((__bf16)a, (__bf16)b);
}

// ---------------------------------------------------------------------------
// K0: weight prep (all swizzled conversions). 240 blocks x 256 = 61440 items.
// ---------------------------------------------------------------------------
__global__ __launch_bounds__(256) void prep_kernel(
    const float* __restrict__ W1, const float* __restrict__ W2,
    const float* __restrict__ Wb,   // W_f2out
    const float* __restrict__ Wc,   // W_dense
    const float* __restrict__ Wf,   // W_in2f
    unsigned* __restrict__ prep)
{
    int i = blockIdx.x * 256 + threadIdx.x;
    if (i < 4096) {                        // W1S (K pad 50->64)
        int sw = i >> 10, ft = (i >> 9) & 1, kh = (i >> 8) & 1;
        int sl = (i >> 2) & 63, j = i & 3;
        int sq = sl >> 4, sm = sl & 15;
        int f = 32 * sw + 16 * ft + sm;
        int c = kh * 16 + 4 * sq + j;
        int k0 = 2 * c, k1 = 2 * c + 1;
        float a = (k0 < 50) ? W1[f * 50 + k0] : 0.0f;
        float b = (k1 < 50) ? W1[f * 50 + k1] : 0.0f;
        prep[i] = pack2f(a, b);
    } else if (i < 12288) {                // W2S
        int s = i - 4096;
        int sw = s >> 11, ft = (s >> 10) & 1, kq = (s >> 8) & 3;
        int sl = (s >> 2) & 63, j = s & 3;
        int sq = sl >> 4, sm = sl & 15;
        int f = 32 * sw + 16 * ft + sm;
        int c = 16 * kq + 4 * sq + j;
        float2 wv = ((const float2*)W2)[f * 64 + c];
        prep[i] = pack2f(wv.x, wv.y);
    } else {                               // f2out / dense / in2f, hi+lo
        int s = i - 12288;
        int L = s >> 14;                   // 0: f2out, 1: dense, 2: in2f
        int r = s & 16383;
        int hl = r >> 13;                  // 0: hi, 1: lo
        int e = r & 8191;
        int sw = e >> 11, ft = (e >> 10) & 1, kq = (e >> 8) & 3;
        int sl = (e >> 2) & 63, j = e & 3;
        int sq = sl >> 4, sm = sl & 15;
        int f = 32 * sw + 16 * ft + sm;
        int c = 16 * kq + 4 * sq + j;
        const float* src = (L == 0) ? Wb : (L == 1) ? Wc : Wf;
        float2 wv = ((const float2*)src)[f * 64 + c];
        if (hl == 0) {
            prep[i] = pack2h((__bf16)wv.x, (__bf16)wv.y);
        } else {
            __bf16 h0 = (__bf16)wv.x, h1 = (__bf16)wv.y;
            prep[i] = pack2f(wv.x - (float)h0, wv.y - (float)h1);
        }
    }
}

// ---------------------------------------------------------------------------
// K1: y = x @ W_in2f^T using preconverted swizzled weights.
// 1024 blocks: (atom-tile of 16) x (f-half of 64). 4 blocks/CU.
// ---------------------------------------------------------------------------
__global__ __launch_bounds__(256, 4) void k1_kernel(
    const float* __restrict__ x,
    const unsigned* __restrict__ Wh, const unsigned* __restrict__ Wl,
    float* __restrict__ yout)
{
    __shared__ __bf16 Ah[16 * 136];
    __shared__ __bf16 Al[16 * 136];

    const int t = threadIdx.x;
    const int atom0 = (blockIdx.x >> 1) * 16;
    const int fh = blockIdx.x & 1;
    const int w = t >> 6, l = t & 63, m = l & 15, q = l >> 4;

    {
        const float4* A4 = (const float4*)(x + (size_t)atom0 * 128);
        unsigned* AhU = (unsigned*)Ah;
        unsigned* AlU = (unsigned*)Al;
        #pragma unroll
        for (int r = 0; r < 2; ++r) {
            int lin4 = r * 256 + t;
            int a = lin4 >> 5, k4 = lin4 & 31;
            float4 xv = A4[lin4];
            __bf16 h0=(__bf16)xv.x, h1=(__bf16)xv.y, h2=(__bf16)xv.z, h3=(__bf16)xv.w;
            int idx = a * 68 + 2 * k4;
            AhU[idx]     = pack2h(h0, h1);
            AhU[idx + 1] = pack2h(h2, h3);
            AlU[idx]     = pack2f(xv.x - (float)h0, xv.y - (float)h1);
            AlU[idx + 1] = pack2f(xv.z - (float)h2, xv.w - (float)h3);
        }
    }
    __syncthreads();

    const int ftile = fh * 4 + w;
    const int f = 16 * ftile + m;
    f32x4_t acc = {0.f, 0.f, 0.f, 0.f};
    #pragma unroll
    for (int kk = 0; kk < 4; ++kk) {
        int off = m * 136 + 32 * kk + 8 * q;
        bf16x8_t ah = *(const bf16x8_t*)&Ah[off];
        bf16x8_t al = *(const bf16x8_t*)&Al[off];
        int wo = (ftile * 4 + kk) * 256 + l * 4;
        bf16x8_t wh = *(const bf16x8_t*)(Wh + wo);
        bf16x8_t wl = *(const bf16x8_t*)(Wl + wo);
        acc = __builtin_amdgcn_mfma_f32_16x16x32_bf16(ah, wh, acc, 0, 0, 0);
        acc = __builtin_amdgcn_mfma_f32_16x16x32_bf16(ah, wl, acc, 0, 0, 0);
        acc = __builtin_amdgcn_mfma_f32_16x16x32_bf16(al, wh, acc, 0, 0, 0);
    }
    #pragma unroll
    for (int r = 0; r < 4; ++r)
        yout[(size_t)(atom0 + 4 * q + r) * 128 + f] = acc[r];
}

// ---------------------------------------------------------------------------
// K2 interaction. 1 atom/block, 256 thr = 4 waves, ONE barrier.
// W2 frags loaded at start; y gathers issued en-bloc after barrier, draining
// under the mt-loop's MFMA/LDS work.
// ---------------------------------------------------------------------------
__global__ __launch_bounds__(256, 4) void interaction_kernel(
    const float* __restrict__ rij, const int* __restrict__ nbrs,
    const float* __restrict__ mask, const float* __restrict__ fij,
    const float* __restrict__ b1, const float* __restrict__ b2,
    const unsigned* __restrict__ W1S,   // swizzled [8][2][64][4] u32
    const unsigned* __restrict__ W2S,   // swizzled [8][4][64][4] u32
    const float* __restrict__ y, float* __restrict__ v)
{
    __shared__ __bf16 Hh[64 * 136];
    __shared__ __bf16 Hl[64 * 136];
    __shared__ float  cb[64];
    __shared__ int    nb[64];

    const int t  = threadIdx.x;
    const int a  = blockIdx.x;
    const int bi = a >> 10;
    const int p0 = a * 64;
    const int w = t >> 6, l = t & 63, m = l & 15, q = l >> 4;
    const int f0 = 32 * w + m;
    const int f1 = f0 + 16;

    // W2 fragments: static addresses, L2-resident -> complete under phase A.
    bf16x8_t w2f0[4], w2f1[4];
    #pragma unroll
    for (int kq = 0; kq < 4; ++kq) {
        w2f0[kq] = *(const bf16x8_t*)(W2S + ((w * 2 + 0) * 4 + kq) * 256 + l * 4);
        w2f1[kq] = *(const bf16x8_t*)(W2S + ((w * 2 + 1) * 4 + kq) * 256 + l * 4);
    }

    if (t < 64) {
        float r = rij[p0 + t];
        cb[t] = (r <= RCUT) ? mask[p0 + t] : 0.0f;
        nb[t] = (bi << 10) + nbrs[p0 + t];
    }

    // ---- phase A: H[n][f] = ssp(fij @ W1^T + b1), wave owns 16 rows ----
    {
        const float* frow = fij + (size_t)(p0 + 16 * w + m) * 50;
        float kv[16];
        #pragma unroll
        for (int j2 = 0; j2 < 4; ++j2) {
            float2 xv = *(const float2*)(frow + 8 * q + 2 * j2);
            kv[2 * j2] = xv.x; kv[2 * j2 + 1] = xv.y;
        }
        #pragma unroll
        for (int j2 = 0; j2 < 4; ++j2) {
            int k = 32 + 8 * q + 2 * j2;
            float2 xv = make_float2(0.f, 0.f);
            if (k < 50) xv = *(const float2*)(frow + k);
            kv[8 + 2 * j2] = xv.x; kv[9 + 2 * j2] = xv.y;
        }
        union { __bf16 e[16]; bf16x8_t v8[2]; } uh, ul;
        #pragma unroll
        for (int k = 0; k < 16; ++k) {
            __bf16 hi = (__bf16)kv[k];
            uh.e[k] = hi;
            ul.e[k] = (__bf16)(kv[k] - (float)hi);
        }
        #pragma unroll 2
        for (int ftile = 0; ftile < 8; ++ftile) {
            float bb = b1[16 * ftile + m];
            f32x4_t acch = {bb, bb, bb, bb};
            f32x4_t accl = {0.f, 0.f, 0.f, 0.f};
            bf16x8_t w0 = *(const bf16x8_t*)(W1S + (ftile * 2 + 0) * 256 + l * 4);
            bf16x8_t w1 = *(const bf16x8_t*)(W1S + (ftile * 2 + 1) * 256 + l * 4);
            acch = __builtin_amdgcn_mfma_f32_16x16x32_bf16(uh.v8[0], w0, acch, 0, 0, 0);
            accl = __builtin_amdgcn_mfma_f32_16x16x32_bf16(ul.v8[0], w0, accl, 0, 0, 0);
            acch = __builtin_amdgcn_mfma_f32_16x16x32_bf16(uh.v8[1], w1, acch, 0, 0, 0);
            accl = __builtin_amdgcn_mfma_f32_16x16x32_bf16(ul.v8[1], w1, accl, 0, 0, 0);
            #pragma unroll
            for (int r = 0; r < 4; ++r) {
                int n = 16 * w + 4 * q + r;
                float hv = sspf(acch[r] + accl[r]);
                __bf16 hh = (__bf16)hv;
                Hh[n * 136 + 16 * ftile + m] = hh;
                Hl[n * 136 + 16 * ftile + m] = (__bf16)(hv - (float)hh);
            }
        }
    }
    __syncthreads();   // the ONLY barrier

    // ---- phase B: issue all 32 y gathers, then MFMAs hide the drain ----
    float yv0[16], yv1[16];
    #pragma unroll
    for (int i = 0; i < 16; ++i) {
        int n = 16 * (i >> 2) + 4 * q + (i & 3);
        const float* yrow = y + (size_t)nb[n] * 128;
        yv0[i] = yrow[f0];
        yv1[i] = yrow[f1];
    }

    const float bb2_0 = b2[f0], bb2_1 = b2[f1];
    float pv0 = 0.0f, pv1 = 0.0f;
    #pragma unroll
    for (int mt = 0; mt < 4; ++mt) {
        f32x4_t a0h = {bb2_0, bb2_0, bb2_0, bb2_0};
        f32x4_t a0l = {0.f, 0.f, 0.f, 0.f};
        f32x4_t a1h = {bb2_1, bb2_1, bb2_1, bb2_1};
        f32x4_t a1l = {0.f, 0.f, 0.f, 0.f};
        #pragma unroll
        for (int kq = 0; kq < 4; ++kq) {
            int hoff = (16 * mt + m) * 136 + 32 * kq + 8 * q;
            bf16x8_t hh = *(const bf16x8_t*)&Hh[hoff];
            bf16x8_t hl = *(const bf16x8_t*)&Hl[hoff];
            a0h = __builtin_amdgcn_mfma_f32_16x16x32_bf16(hh, w2f0[kq], a0h, 0, 0, 0);
            a0l = __builtin_amdgcn_mfma_f32_16x16x32_bf16(hl, w2f0[kq], a0l, 0, 0, 0);
            a1h = __builtin_amdgcn_mfma_f32_16x16x32_bf16(hh, w2f1[kq], a1h, 0, 0, 0);
            a1l = __builtin_amdgcn_mfma_f32_16x16x32_bf16(hl, w2f1[kq], a1l, 0, 0, 0);
        }
        #pragma unroll
        for (int r = 0; r < 4; ++r) {
            int n = 16 * mt + 4 * q + r;
            float cn = cb[n];
            float s0 = a0h[r] + a0l[r];
            float s1 = a1h[r] + a1l[r];
            pv0 = fmaf(cn * yv0[mt * 4 + r], s0, pv0);
            pv1 = fmaf(cn * yv1[mt * 4 + r], s1, pv1);
        }
    }
    pv0 += __shfl_xor(pv0, 16);
    pv0 += __shfl_xor(pv0, 32);
    pv1 += __shfl_xor(pv1, 16);
    pv1 += __shfl_xor(pv1, 32);
    if (l < 16) {
        v[(size_t)a * 128 + f0] = pv0;
        v[(size_t)a * 128 + f1] = pv1;
    }
}

// ---------------------------------------------------------------------------
// K3: two chained dense layers, swizzled coalesced weight loads.
// ---------------------------------------------------------------------------
__global__ __launch_bounds__(256, 4) void mgemm2_kernel(
    const float* A,
    const unsigned* __restrict__ W1h, const unsigned* __restrict__ W1l,
    const float* __restrict__ bias1, int nssp1,
    const unsigned* __restrict__ W2h, const unsigned* __restrict__ W2l,
    const float* __restrict__ bias2, int nssp2,
    float* C)
{
    extern __shared__ float smf[];
    __bf16* Ah = (__bf16*)smf;              // [16][136]
    __bf16* Al = (__bf16*)(smf + 1088);
    unsigned* AhU = (unsigned*)Ah;
    unsigned* AlU = (unsigned*)Al;

    const int t = threadIdx.x;
    const int atom0 = blockIdx.x * 16;
    const int w = t >> 6, l = t & 63, m = l & 15, q = l >> 4;

    {
        const float4* A4 = (const float4*)(A + (size_t)atom0 * 128);
        #pragma unroll
        for (int r = 0; r < 2; ++r) {
            int lin4 = r * 256 + t;
            int a = lin4 >> 5, k4 = lin4 & 31;
            float4 xv = A4[lin4];
            __bf16 h0=(__bf16)xv.x, h1=(__bf16)xv.y, h2=(__bf16)xv.z, h3=(__bf16)xv.w;
            int idx = a * 68 + 2 * k4;
            AhU[idx]     = pack2h(h0, h1);
            AhU[idx + 1] = pack2h(h2, h3);
            AlU[idx]     = pack2f(xv.x - (float)h0, xv.y - (float)h1);
            AlU[idx + 1] = pack2f(xv.z - (float)h2, xv.w - (float)h3);
        }
    }
    __syncthreads();

    bf16x8_t ah[4], al[4];
    #pragma unroll
    for (int kk = 0; kk < 4; ++kk) {
        int off = m * 136 + 32 * kk + 8 * q;
        ah[kk] = *(const bf16x8_t*)&Ah[off];
        al[kk] = *(const bf16x8_t*)&Al[off];
    }
    f32x4_t acc[2];
    int fidx[2];
    #pragma unroll
    for (int ft = 0; ft < 2; ++ft) {
        fidx[ft] = 16 * (2 * w + ft) + m;
        float b = bias1 ? bias1[fidx[ft]] : 0.0f;
        acc[ft] = (f32x4_t){b, b, b, b};
    }
    #pragma unroll
    for (int ft = 0; ft < 2; ++ft) {
        #pragma unroll
        for (int kk = 0; kk < 4; ++kk) {
            int wo = ((2 * w + ft) * 4 + kk) * 256 + l * 4;
            bf16x8_t wh = *(const bf16x8_t*)(W1h + wo);
            bf16x8_t wl = *(const bf16x8_t*)(W1l + wo);
            acc[ft] = __builtin_amdgcn_mfma_f32_16x16x32_bf16(ah[kk], wh, acc[ft], 0, 0, 0);
            acc[ft] = __builtin_amdgcn_mfma_f32_16x16x32_bf16(ah[kk], wl, acc[ft], 0, 0, 0);
            acc[ft] = __builtin_amdgcn_mfma_f32_16x16x32_bf16(al[kk], wh, acc[ft], 0, 0, 0);
        }
    }
    #pragma unroll
    for (int ft = 0; ft < 2; ++ft)
        #pragma unroll
        for (int r = 0; r < 4; ++r) {
            float o = acc[ft][r];
            if (nssp1 >= 1) o = sspf(o);
            if (nssp1 >= 2) o = sspf(o);
            acc[ft][r] = o;
        }

    __syncthreads();
    #pragma unroll
    for (int ft = 0; ft < 2; ++ft)
        #pragma unroll
        for (int r = 0; r < 4; ++r) {
            float o = acc[ft][r];
            __bf16 hh = (__bf16)o;
            Ah[(4 * q + r) * 136 + fidx[ft]] = hh;
            Al[(4 * q + r) * 136 + fidx[ft]] = (__bf16)(o - (float)hh);
        }
    __syncthreads();

    #pragma unroll
    for (int kk = 0; kk < 4; ++kk) {
        int off = m * 136 + 32 * kk + 8 * q;
        ah[kk] = *(const bf16x8_t*)&Ah[off];
        al[kk] = *(const bf16x8_t*)&Al[off];
    }
    #pragma unroll
    for (int ft = 0; ft < 2; ++ft) {
        float b = bias2 ? bias2[fidx[ft]] : 0.0f;
        acc[ft] = (f32x4_t){b, b, b, b};
    }
    #pragma unroll
    for (int ft = 0; ft < 2; ++ft) {
        #pragma unroll
        for (int kk = 0; kk < 4; ++kk) {
            int wo = ((2 * w + ft) * 4 + kk) * 256 + l * 4;
            bf16x8_t wh = *(const bf16x8_t*)(W2h + wo);
            bf16x8_t wl = *(const bf16x8_t*)(W2l + wo);
            acc[ft] = __builtin_amdgcn_mfma_f32_16x16x32_bf16(ah[kk], wh, acc[ft], 0, 0, 0);
            acc[ft] = __builtin_amdgcn_mfma_f32_16x16x32_bf16(ah[kk], wl, acc[ft], 0, 0, 0);
            acc[ft] = __builtin_amdgcn_mfma_f32_16x16x32_bf16(al[kk], wh, acc[ft], 0, 0, 0);
        }
    }
    #pragma unroll
    for (int ft = 0; ft < 2; ++ft)
        #pragma unroll
        for (int r = 0; r < 4; ++r) {
            float o = acc[ft][r];
            if (nssp2 >= 1) o = sspf(o);
            if (nssp2 >= 2) o = sspf(o);
            C[(size_t)(atom0 + 4 * q + r) * 128 + fidx[ft]] = o;
        }
}

// ---------------------------------------------------------------------------
extern "C" void kernel_launch(void* const* d_in, const int* in_sizes, int n_in,
                              void* d_out, int out_size, void* d_ws, size_t ws_size,
                              hipStream_t stream) {
    const float* x        = (const float*)d_in[0];
    const float* rij      = (const float*)d_in[1];
    const int*   nbrs     = (const int*)  d_in[2];
    const float* mask     = (const float*)d_in[3];
    const float* fij      = (const float*)d_in[4];
    const float* W_in2f   = (const float*)d_in[5];
    const float* W_f1     = (const float*)d_in[6];
    const float* b_f1     = (const float*)d_in[7];
    const float* W_f2     = (const float*)d_in[8];
    const float* b_f2     = (const float*)d_in[9];
    const float* W_f2out  = (const float*)d_in[10];
    const float* b_f2out  = (const float*)d_in[11];
    const float* W_dense  = (const float*)d_in[12];
    const float* b_dense  = (const float*)d_in[13];
    float* out = (float*)d_out;

    // ws: y [8192][128] f32 @0 (4 MB) | prep 240 KB @4 MB.
    float*    y    = (float*)d_ws;
    unsigned* prep = (unsigned*)((char*)d_ws + (4u << 20));
    const unsigned* W1S    = prep;
    const unsigned* W2S    = prep + 4096;
    const unsigned* f2o_h  = prep + 12288, *f2o_l  = prep + 20480;
    const unsigned* den_h  = prep + 28672, *den_l  = prep + 36864;
    const unsigned* in2f_h = prep + 45056, *in2f_l = prep + 53248;

    const int MG2_LDS = 2176 * 4;    // 8704 B

    // K0: all weight prep (61440 items)
    prep_kernel<<<240, 256, 0, stream>>>(W_f1, W_f2, W_f2out, W_dense, W_in2f, prep);
    // K1: y = x @ W_in2f^T  (preconverted weights, 1024 blocks)
    k1_kernel<<<1024, 256, 0, stream>>>(x, in2f_h, in2f_l, y);
    // K2: filter net + cutoff + gather + aggregate -> d_out (v)
    interaction_kernel<<<8192, 256, 0, stream>>>(
        rij, nbrs, mask, fij, b_f1, b_f2, W1S, W2S, y, out);
    // K3: out = ssp(ssp(v@W_f2out^T+b)) @ W_dense^T + b_dense, in-place
    mgemm2_kernel<<<512, 256, MG2_LDS, stream>>>(
        out, f2o_h, f2o_l, b_f2out, 2, den_h, den_l, b_dense, 0, out);
}